// Round 7
// baseline (483.046 us; speedup 1.0000x reference)
//
#include <hip/hip_runtime.h>
#include <cstddef>
#include <cstdint>

#define SLEN 1024
#define DIM  768
#define NJ   32
#define NSPEC (NJ * DIM)          // 24576 columns of Y
#define MROWS (2 * SLEN)          // 2048
#define NP    (MROWS * DIM)       // floats per partial (1572864)
#define SKAR  2                   // ar_u split-K
#define SK2   4                   // gemm2 split-K

typedef _Float16 f16;
typedef _Float16 f16x8 __attribute__((ext_vector_type(8)));
typedef _Float16 f16x4 __attribute__((ext_vector_type(4)));
typedef float    f32x4 __attribute__((ext_vector_type(4)));

// async global->LDS, 16B per lane. LDS dest = wave-uniform base + lane*16.
__device__ __forceinline__ void async16(f16* lds, const f16* g) {
    __builtin_amdgcn_global_load_lds(
        (const __attribute__((address_space(1))) unsigned int*)g,
        (__attribute__((address_space(3))) unsigned int*)lds, 16, 0, 0);
}

// ---------------------------------------------------------------------------
// R8[j][i]: reversed zero-padded filter (NO sigma; sigma folded into WAt).
// R8[j][i] = F[j][1031-i] for 8<=i<1032 else 0; F[j][tau] = V[tau,k] (j<16),
// V[tau,k]*(-1)^tau (j>=16). Also zeroes the zb scratch.
// ---------------------------------------------------------------------------
__global__ __launch_bounds__(256) void build_r8(
    const float* __restrict__ V, f16* __restrict__ R8, float* __restrict__ zb)
{
    int g = blockIdx.x * 256 + threadIdx.x;   // 0..49151
    if (g < 256) zb[g] = 0.f;
    int j = g / 1536, i = g % 1536;
    int k = j & 15;
    int tau = 1031 - i;
    float val = 0.f;
    if (tau >= 0 && tau < 1024) {
        val = V[tau * 16 + k];
        if (j >= 16 && (tau & 1)) val = -val;
    }
    R8[j * 1536 + i] = (f16)val;
}

// x (2,1024,768) f32 -> x16 [2048][768] f16 (row-major cast only)
__global__ __launch_bounds__(256) void pack_x16(
    const float* __restrict__ x, f16* __restrict__ x16)
{
    int g = blockIdx.x * 256 + threadIdx.x;   // 0..393215 float4s
    float4 v = ((const float4*)x)[g];
    f16x4 h = {(f16)v.x, (f16)v.y, (f16)v.z, (f16)v.w};
    ((f16x4*)x16)[g] = h;
}

// ---------------------------------------------------------------------------
// WAt[(j*768+o)][d] = sigma_k^0.25 * M_{pp/pm}[k][d][o]  (n-major, f16)
// ---------------------------------------------------------------------------
__global__ __launch_bounds__(256) void pack_wA(
    const float* __restrict__ Mpp, const float* __restrict__ Mpm,
    const float* __restrict__ sigma, f16* __restrict__ WAt)
{
    __shared__ float tile[32][33];
    const int d0 = blockIdx.x * 32, o0 = blockIdx.y * 32, j = blockIdx.z;
    const int k = j & 15;
    const float* src = (j < 16 ? Mpp : Mpm) + (size_t)k * DIM * DIM;
    const float sc = powf(sigma[k], 0.25f);
    const int tx = threadIdx.x & 31, ty = threadIdx.x >> 5;
#pragma unroll
    for (int r = 0; r < 4; ++r) {
        int dl = ty + r * 8;
        tile[dl][tx] = src[(size_t)(d0 + dl) * DIM + o0 + tx];
    }
    __syncthreads();
#pragma unroll
    for (int r = 0; r < 4; ++r) {
        int ol = ty + r * 8;
        WAt[(size_t)(j * DIM + o0 + ol) * DIM + d0 + tx] = (f16)(sc * tile[tx][ol]);
    }
}

// Mut[o][i*768+d] = M_u[i][d][o]  (n-major, f16, K=2304)
__global__ __launch_bounds__(256) void pack_mu(
    const float* __restrict__ Mu, f16* __restrict__ Mut)
{
    __shared__ float tile[32][33];
    const int d0 = blockIdx.x * 32, o0 = blockIdx.y * 32, i = blockIdx.z;
    const float* src = Mu + (size_t)i * DIM * DIM;
    const int tx = threadIdx.x & 31, ty = threadIdx.x >> 5;
#pragma unroll
    for (int r = 0; r < 4; ++r) {
        int dl = ty + r * 8;
        tile[dl][tx] = src[(size_t)(d0 + dl) * DIM + o0 + tx];
    }
    __syncthreads();
#pragma unroll
    for (int r = 0; r < 4; ++r) {
        int ol = ty + r * 8;
        Mut[(size_t)(o0 + ol) * 2304 + i * DIM + d0 + tx] = (f16)tile[tx][ol];
    }
}

// My (768,2,768) f32 -> f16: My16t[o][c], c = i*768+d
__global__ __launch_bounds__(256) void pack_my(
    const float* __restrict__ My, f16* __restrict__ My16t)
{
    int g = blockIdx.x * 256 + threadIdx.x;
    float4 v = ((const float4*)My)[g];
    f16x4 h = {(f16)v.x, (f16)v.y, (f16)v.z, (f16)v.w};
    ((f16x4*)My16t)[g] = h;
}

// ---------------------------------------------------------------------------
// GEMM-A: Yt[n][m] = sum_d x16[m][d] * WAt[n][d]   (M=2048, N=24576, K=768)
// No guards/shifts. Epilogue: LDS transpose -> coalesced Yt rows.
// ---------------------------------------------------------------------------
__global__ __launch_bounds__(256) void gemmA(
    const f16* __restrict__ x16, const f16* __restrict__ WAt,
    f16* __restrict__ Yt)
{
    __shared__ f16 smem[128 * 132];           // 33792 B; As/Bs overlay Ct
    f16* As = smem;                           // 8192 halfs
    f16* Bs = smem + 8192;                    // 8192 halfs
    const int n0 = blockIdx.x * 128;
    const int m0 = blockIdx.y * 128;
    const int tid = threadIdx.x;
    const int lane = tid & 63, w = tid >> 6;
    const int wr = w >> 1, wc = w & 1;
    const int lrow = lane & 15, lgrp = lane >> 4;
    const int rrel = lane >> 3, slotw = lane & 7;
    const int colh = (slotw ^ rrel) * 8;

    f32x4 acc[4][4];
#pragma unroll
    for (int mi = 0; mi < 4; ++mi)
#pragma unroll
        for (int ni = 0; ni < 4; ++ni) acc[mi][ni] = (f32x4){0.f, 0.f, 0.f, 0.f};

#pragma unroll 1
    for (int kt = 0; kt < 12; ++kt) {
        const int c0 = kt * 64;
#pragma unroll
        for (int q = 0; q < 4; ++q) {
            int row = w * 32 + q * 8 + rrel;
            async16(&As[(w * 32 + q * 8) * 64],
                    x16 + (size_t)(m0 + row) * DIM + c0 + colh);
            async16(&Bs[(w * 32 + q * 8) * 64],
                    WAt + (size_t)(n0 + row) * DIM + c0 + colh);
        }
        __syncthreads();
#pragma unroll
        for (int ks = 0; ks < 2; ++ks) {
            f16x8 af[4], bf[4];
#pragma unroll
            for (int mi = 0; mi < 4; ++mi) {
                int r = wr * 64 + mi * 16 + lrow;
                int slot = (ks * 4 + lgrp) ^ (r & 7);
                af[mi] = *(const f16x8*)&As[r * 64 + slot * 8];
            }
#pragma unroll
            for (int ni = 0; ni < 4; ++ni) {
                int col = wc * 64 + ni * 16 + lrow;
                int slot = (ks * 4 + lgrp) ^ (col & 7);
                bf[ni] = *(const f16x8*)&Bs[col * 64 + slot * 8];
            }
#pragma unroll
            for (int mi = 0; mi < 4; ++mi)
#pragma unroll
                for (int ni = 0; ni < 4; ++ni)
                    acc[mi][ni] = __builtin_amdgcn_mfma_f32_16x16x32_f16(
                        af[mi], bf[ni], acc[mi][ni], 0, 0, 0);
        }
        __syncthreads();
    }
    // transpose epilogue: Ct[n_local][m_local] (stride 132), then coalesced out
#pragma unroll
    for (int mi = 0; mi < 4; ++mi)
#pragma unroll
        for (int ni = 0; ni < 4; ++ni) {
            int col = wc * 64 + ni * 16 + lrow;          // n_local
            int rowm = wr * 64 + mi * 16 + lgrp * 4;     // m_local
            f16x4 hv = {(f16)acc[mi][ni][0], (f16)acc[mi][ni][1],
                        (f16)acc[mi][ni][2], (f16)acc[mi][ni][3]};
            *(f16x4*)&smem[col * 132 + rowm] = hv;
        }
    __syncthreads();
    {
        int row = tid >> 1, half = tid & 1;
        const f16* cr = &smem[row * 132 + half * 64];
        f16* gp = Yt + (size_t)(n0 + row) * MROWS + m0 + half * 64;
#pragma unroll
        for (int e = 0; e < 16; ++e)
            *(f16x4*)&gp[e * 4] = *(const f16x4*)&cr[e * 4];
    }
}

// ---------------------------------------------------------------------------
// CONV-B: P[jg][m][o] = sum_{j in jg} sum_{t<=l-2} F_j[(l-2)-t] * Yt[j*768+o][b*1024+t]
// Shift-by-2 folded into the Toeplitz diagonal (cpb = 906 - D).
// A from 8 shift-aligned reversed-filter copies (Cp); B via async16.
// blockIdx.y ^ 7: heavy (large-l0) tiles dispatch first.
// ---------------------------------------------------------------------------
__global__ __launch_bounds__(256) void conv_b(
    const f16* __restrict__ Yt, const f16* __restrict__ R8,
    float* __restrict__ P)
{
    __shared__ f16 Bs[128 * 64];
    __shared__ f16 Cp[8 * 264];
    const int o0 = blockIdx.x * 128;
    const int meff = blockIdx.y ^ 7;          // heavy-first within each batch
    const int b = meff >> 3, yp = meff & 7;
    const int l0 = yp * 128, m0 = meff * 128;
    const int jg = blockIdx.z;
    const int tid = threadIdx.x;
    const int lane = tid & 63, w = tid >> 6;
    const int wr = w >> 1, wc = w & 1;
    const int lrow = lane & 15, lgrp = lane >> 4;
    const int rrel = lane >> 3, slotw = lane & 7;
    const int colh = (slotw ^ rrel) * 8;
    const int cch = tid / 33, cjc = (tid % 33) * 8;

    f32x4 acc[4][4];
#pragma unroll
    for (int mi = 0; mi < 4; ++mi)
#pragma unroll
        for (int ni = 0; ni < 4; ++ni) acc[mi][ni] = (f32x4){0.f, 0.f, 0.f, 0.f};

    const int nkt = yp * 2 + 2;
#pragma unroll 1
    for (int jj = 0; jj < 8; ++jj) {
        const int j = jg * 8 + jj;
        const f16* R8j = R8 + j * 1536;
        const f16* Yb = Yt + ((size_t)(j * DIM + o0)) * MROWS + b * SLEN;
#pragma unroll 1
        for (int tt = 0; tt < nkt; ++tt) {
            const int t0 = tt * 64;
            const int cpb = 906 - (l0 - t0);  // 904-D with shift-2 folded
            {
                const f16* gp = R8j + cpb + cjc - cch;
                f16x8 v;
#pragma unroll
                for (int e = 0; e < 8; ++e) v[e] = gp[e];
                *(f16x8*)&Cp[cch * 264 + cjc] = v;
                if (tid < 8) {
                    int ch2 = tid + 256;
                    int c2 = ch2 / 33, jc2 = (ch2 % 33) * 8;
                    const f16* gp2 = R8j + cpb + jc2 - c2;
                    f16x8 v2;
#pragma unroll
                    for (int e = 0; e < 8; ++e) v2[e] = gp2[e];
                    *(f16x8*)&Cp[c2 * 264 + jc2] = v2;
                }
            }
#pragma unroll
            for (int q = 0; q < 4; ++q) {
                int row = w * 32 + q * 8 + rrel;
                async16(&Bs[(w * 32 + q * 8) * 64],
                        Yb + (size_t)row * MROWS + t0 + colh);
            }
            __syncthreads();
#pragma unroll
            for (int ks = 0; ks < 2; ++ks) {
                f16x8 af[4], bf[4];
#pragma unroll
                for (int mi = 0; mi < 4; ++mi) {
                    int r = wr * 64 + mi * 16 + lrow;
                    int h = 127 - r + ks * 32 + lgrp * 8;
                    int c = (-h) & 7;
                    af[mi] = *(const f16x8*)&Cp[c * 265 + h];
                }
#pragma unroll
                for (int ni = 0; ni < 4; ++ni) {
                    int col = wc * 64 + ni * 16 + lrow;
                    int slot = (ks * 4 + lgrp) ^ (col & 7);
                    bf[ni] = *(const f16x8*)&Bs[col * 64 + slot * 8];
                }
#pragma unroll
                for (int mi = 0; mi < 4; ++mi)
#pragma unroll
                    for (int ni = 0; ni < 4; ++ni)
                        acc[mi][ni] = __builtin_amdgcn_mfma_f32_16x16x32_f16(
                            af[mi], bf[ni], acc[mi][ni], 0, 0, 0);
            }
            __syncthreads();
        }
    }
    float* Pp = P + (size_t)jg * NP;
#pragma unroll
    for (int mi = 0; mi < 4; ++mi)
#pragma unroll
        for (int ni = 0; ni < 4; ++ni) {
            int m = m0 + wr * 64 + mi * 16 + lgrp * 4;
            int col = o0 + wc * 64 + ni * 16 + lrow;
#pragma unroll
            for (int q = 0; q < 4; ++q)
                Pp[(size_t)(m + q) * DIM + col] = acc[mi][ni][q];
        }
}

// ---------------------------------------------------------------------------
// ar_u GEMM: P[4+s][m][o] partial of sum_i x16[m-i][:] . Mut[o][i*768+:]
// ---------------------------------------------------------------------------
__global__ __launch_bounds__(256) void ar_gemm(
    const f16* __restrict__ x16, const f16* __restrict__ Mut,
    const f16* __restrict__ zb16, float* __restrict__ P)
{
    __shared__ f16 As[128 * 64];
    __shared__ f16 Bs[128 * 64];
    const int n0 = blockIdx.x * 128;
    const int m0 = blockIdx.y * 128;
    const int s  = blockIdx.z;
    const int tid = threadIdx.x;
    const int lane = tid & 63, w = tid >> 6;
    const int wr = w >> 1, wc = w & 1;
    const int lrow = lane & 15, lgrp = lane >> 4;
    const int rrel = lane >> 3, slotw = lane & 7;
    const int colh = (slotw ^ rrel) * 8;

    f32x4 acc[4][4];
#pragma unroll
    for (int mi = 0; mi < 4; ++mi)
#pragma unroll
        for (int ni = 0; ni < 4; ++ni) acc[mi][ni] = (f32x4){0.f, 0.f, 0.f, 0.f};

    for (int kt = s * 18; kt < (s + 1) * 18; ++kt) {
        const int c0 = kt * 64;
        const int i = c0 / DIM;               // tap 0..2, tile-uniform
        const int co = c0 - i * DIM;
#pragma unroll
        for (int q = 0; q < 4; ++q) {
            int row = w * 32 + q * 8 + rrel;
            int m = m0 + row;
            int l = m & (SLEN - 1);
            const f16* src = (l >= i)
                ? x16 + (size_t)(m - i) * DIM + co + colh : zb16;
            async16(&As[(w * 32 + q * 8) * 64], src);
        }
#pragma unroll
        for (int q = 0; q < 4; ++q) {
            int row = w * 32 + q * 8 + rrel;
            async16(&Bs[(w * 32 + q * 8) * 64],
                    Mut + (size_t)(n0 + row) * 2304 + c0 + colh);
        }
        __syncthreads();
#pragma unroll
        for (int ks = 0; ks < 2; ++ks) {
            f16x8 af[4], bf[4];
#pragma unroll
            for (int mi = 0; mi < 4; ++mi) {
                int r = wr * 64 + mi * 16 + lrow;
                int slot = (ks * 4 + lgrp) ^ (r & 7);
                af[mi] = *(const f16x8*)&As[r * 64 + slot * 8];
            }
#pragma unroll
            for (int ni = 0; ni < 4; ++ni) {
                int col = wc * 64 + ni * 16 + lrow;
                int slot = (ks * 4 + lgrp) ^ (col & 7);
                bf[ni] = *(const f16x8*)&Bs[col * 64 + slot * 8];
            }
#pragma unroll
            for (int mi = 0; mi < 4; ++mi)
#pragma unroll
                for (int ni = 0; ni < 4; ++ni)
                    acc[mi][ni] = __builtin_amdgcn_mfma_f32_16x16x32_f16(
                        af[mi], bf[ni], acc[mi][ni], 0, 0, 0);
        }
        __syncthreads();
    }
    float* Pp = P + (size_t)(4 + s) * NP;
#pragma unroll
    for (int mi = 0; mi < 4; ++mi)
#pragma unroll
        for (int ni = 0; ni < 4; ++ni) {
            int m = m0 + wr * 64 + mi * 16 + lgrp * 4;
            int col = n0 + wc * 64 + ni * 16 + lrow;
#pragma unroll
            for (int q = 0; q < 4; ++q)
                Pp[(size_t)(m + q) * DIM + col] = acc[mi][ni][q];
        }
}

// z = sum of 6 partials (4 conv_b j-groups + 2 ar splits); emit z f32 + z16
__global__ __launch_bounds__(256) void zreduce(
    const float* __restrict__ P, float* __restrict__ z, f16* __restrict__ z16)
{
    int g = blockIdx.x * 256 + threadIdx.x;   // 0..393215 float4s
    const float4* P4 = (const float4*)P;
    float4 s = P4[g];
#pragma unroll
    for (int i = 1; i < 6; ++i) {
        float4 t = P4[g + (size_t)i * (NP / 4)];
        s.x += t.x; s.y += t.y; s.z += t.z; s.w += t.w;
    }
    ((float4*)z)[g] = s;
    f16x4 h = {(f16)s.x, (f16)s.y, (f16)s.z, (f16)s.w};
    ((f16x4*)z16)[g] = h;
}

// ---------------------------------------------------------------------------
// gemm2 (fp16 MFMA, split-K=4): P2[s][m][o] partial of
//   sum_{i=0,1} z[m-1-i][d] * My[o][i*768+d]
// ---------------------------------------------------------------------------
__global__ __launch_bounds__(256) void gemm2_mfma(
    const f16* __restrict__ z16, const f16* __restrict__ My16t,
    const f16* __restrict__ zb16, float* __restrict__ P2)
{
    __shared__ f16 As[128 * 64];
    __shared__ f16 Bs[128 * 64];
    const int n0 = blockIdx.x * 128;
    const int m0 = blockIdx.y * 128;
    const int s  = blockIdx.z;
    const int tid = threadIdx.x;
    const int lane = tid & 63, w = tid >> 6;
    const int wr = w >> 1, wc = w & 1;
    const int lrow = lane & 15, lgrp = lane >> 4;
    const int rrel = lane >> 3, slotw = lane & 7;
    const int colh = (slotw ^ rrel) * 8;

    f32x4 acc[4][4];
#pragma unroll
    for (int mi = 0; mi < 4; ++mi)
#pragma unroll
        for (int ni = 0; ni < 4; ++ni) acc[mi][ni] = (f32x4){0.f, 0.f, 0.f, 0.f};

    for (int kt = s * 6; kt < (s + 1) * 6; ++kt) {
        const int c0 = kt * 64;
        const int i = (c0 >= DIM) ? 1 : 0;
        const int sh = i + 1;
        const int co = c0 - i * DIM;
#pragma unroll
        for (int q = 0; q < 4; ++q) {
            int row = w * 32 + q * 8 + rrel;
            int m = m0 + row;
            int l = m & (SLEN - 1);
            const f16* src = (l >= sh)
                ? z16 + (size_t)(m - sh) * DIM + co + colh : zb16;
            async16(&As[(w * 32 + q * 8) * 64], src);
        }
#pragma unroll
        for (int q = 0; q < 4; ++q) {
            int row = w * 32 + q * 8 + rrel;
            async16(&Bs[(w * 32 + q * 8) * 64],
                    My16t + (size_t)(n0 + row) * 1536 + c0 + colh);
        }
        __syncthreads();
#pragma unroll
        for (int ks = 0; ks < 2; ++ks) {
            f16x8 af[4], bf[4];
#pragma unroll
            for (int mi = 0; mi < 4; ++mi) {
                int r = wr * 64 + mi * 16 + lrow;
                int slot = (ks * 4 + lgrp) ^ (r & 7);
                af[mi] = *(const f16x8*)&As[r * 64 + slot * 8];
            }
#pragma unroll
            for (int ni = 0; ni < 4; ++ni) {
                int col = wc * 64 + ni * 16 + lrow;
                int slot = (ks * 4 + lgrp) ^ (col & 7);
                bf[ni] = *(const f16x8*)&Bs[col * 64 + slot * 8];
            }
#pragma unroll
            for (int mi = 0; mi < 4; ++mi)
#pragma unroll
                for (int ni = 0; ni < 4; ++ni)
                    acc[mi][ni] = __builtin_amdgcn_mfma_f32_16x16x32_f16(
                        af[mi], bf[ni], acc[mi][ni], 0, 0, 0);
        }
        __syncthreads();
    }
    float* Pp = P2 + (size_t)s * NP;
#pragma unroll
    for (int mi = 0; mi < 4; ++mi)
#pragma unroll
        for (int ni = 0; ni < 4; ++ni) {
            int m = m0 + wr * 64 + mi * 16 + lgrp * 4;
            int col = n0 + wc * 64 + ni * 16 + lrow;
#pragma unroll
            for (int q = 0; q < 4; ++q)
                Pp[(size_t)(m + q) * DIM + col] = acc[mi][ni][q];
        }
}

// out = z + sum of 4 gemm2 partials
__global__ __launch_bounds__(256) void final_add(
    const float* __restrict__ z, const float* __restrict__ P2,
    float* __restrict__ out)
{
    int g = blockIdx.x * 256 + threadIdx.x;
    const float4* z4 = (const float4*)z;
    const float4* Q  = (const float4*)P2;
    float4 s = z4[g];
#pragma unroll
    for (int i = 0; i < SK2; ++i) {
        float4 t = Q[g + (size_t)i * (NP / 4)];
        s.x += t.x; s.y += t.y; s.z += t.z; s.w += t.w;
    }
    ((float4*)out)[g] = s;
}

extern "C" void kernel_launch(void* const* d_in, const int* in_sizes, int n_in,
                              void* d_out, int out_size, void* d_ws, size_t ws_size,
                              hipStream_t stream)
{
    const float* inputs = (const float*)d_in[0];   // (2,1024,768)
    const float* sigma  = (const float*)d_in[1];   // (16,)
    const float* V      = (const float*)d_in[2];   // (1024,16)
    const float* Mu     = (const float*)d_in[3];   // (3,768,768)
    const float* Mpp    = (const float*)d_in[4];   // (16,768,768)
    const float* Mpm    = (const float*)d_in[5];   // (16,768,768)
    const float* My     = (const float*)d_in[6];   // (768,2,768)
    float* out = (float*)d_out;

    char* base = (char*)d_ws;
    float* zb   = (float*)(base);                  //   1 KB zeros
    f16* R8     = (f16*)(base + 1024);             //  96 KB
    f16* x16    = (f16*)(base + 99328);            //   3 MB
    f16* WAt    = (f16*)(base + 3245056);          // 37.7 MB
    f16* Mut    = (f16*)(base + 40993792);         // 3.5 MB
    f16* My16t  = (f16*)(base + 44532736);         // 2.36 MB
    f16* Yt     = (f16*)(base + 46892032);         // 100.7 MB
    float* P    = (float*)(base + 147555328);      // 6 x 6.29 MB partials
    float* z    = (float*)(base + 185304064);      // 6.29 MB
    f16* z16    = (f16*)(base + 191595520);        // 3.1 MB (ends 194.7 MB)
    const f16* zb16 = (const f16*)zb;

    build_r8<<<192, 256, 0, stream>>>(V, R8, zb);
    pack_x16<<<1536, 256, 0, stream>>>(inputs, x16);
    pack_wA<<<dim3(24, 24, 32), 256, 0, stream>>>(Mpp, Mpm, sigma, WAt);
    pack_mu<<<dim3(24, 24, 3), 256, 0, stream>>>(Mu, Mut);
    pack_my<<<1152, 256, 0, stream>>>(My, My16t);
    gemmA<<<dim3(192, 16), 256, 0, stream>>>(x16, WAt, Yt);
    conv_b<<<dim3(6, 16, 4), 256, 0, stream>>>(Yt, R8, P);
    ar_gemm<<<dim3(6, 16, SKAR), 256, 0, stream>>>(x16, Mut, zb16, P);
    zreduce<<<1536, 256, 0, stream>>>(P, z, z16);
    gemm2_mfma<<<dim3(6, 16, SK2), 256, 0, stream>>>(z16, My16t, zb16, P);
    final_add<<<1536, 256, 0, stream>>>(z, P, out);
}